// Round 6
// baseline (94.698 us; speedup 1.0000x reference)
//
#include <hip/hip_runtime.h>

// TiledEquivariantMLP — live-path-only implementation, v4.
// Only the l=0 (scalar) channel affects the output (gates y0[:,64:256] feed
// only l>0 irreps, which are dead). Per atom:
//   h1 = silu(x[:, :32] @ W0_0[:, :64] / sqrt(32))
//   h2 = silu(h1 @ W1_0[:, :64] / 8)
//   out[b, c] = (sum_{atoms in class c} h2) @ Wout[c] / 8     (linear => hoist)
//
// v4 vs v3: weight columns live in VGPRs (lane o holds W0[:,o], W1[:,o]),
// loaded once per block via coalesced 256B/wave global loads (L2-hot).
// Kills the 24KB LDS weight staging and the per-m ds_read_b32 in both inner
// loops -> group critical path ~1710 -> ~1150 cyc (LDS-issue-bound).
//
// Grid: (10 classes, 32 batches). Each block owns out[b, c*128:(c+1)*128]
// exclusively -> no atomics, no output pre-zero, no workspace.

#define NCLS  10
#define NB    32
#define NATOM 512
#define DIN   272

__global__ __launch_bounds__(256) void eqmlp_fused(
    const float* __restrict__ x,       // (32, 512, 272)
    const float* __restrict__ W0,      // (10, 32, 256)  use cols [0,64)
    const float* __restrict__ W1,      // (10, 64, 256)  use cols [0,64)
    const float* __restrict__ Wo,      // (10, 64, 128)
    const int*   __restrict__ mapping, // (32, 512) values 0..10
    float*       __restrict__ out)     // (32, 1280)
{
    const int c    = blockIdx.x;
    const int b    = blockIdx.y;
    const int tid  = threadIdx.x;
    const int w    = tid >> 6;   // wave 0..3
    const int lane = tid & 63;

    __shared__ __align__(16) float xbuf [4][32 * 4]; // per-wave, m-major x4 atoms
    __shared__ __align__(16) float h1buf[4][64 * 4]; // per-wave
    __shared__ __align__(16) float hsum[4][64];      // per-wave atom-summed h2
    __shared__ __align__(16) float fin[2][128];
    __shared__ int alist[NATOM];                     // compacted matched atoms
    __shared__ int scnt[8], soff[8], stotal;

    // ---- mapping loads (independent of everything else) ----
    const int* map_b = mapping + b * NATOM;
    const int  mv0 = map_b[w * 128 + lane];
    const int  mv1 = map_b[w * 128 + 64 + lane];

    // ---- weight columns -> VGPRs (lane o = output column o) ----
    // Coalesced: for fixed m, lanes 0..63 read consecutive floats (256B/wave).
    // Issued before compaction; latency hides under the barriers below.
    float w0reg[32], w1reg[64];
    {
        const float* W0g = W0 + (size_t)c * 32 * 256 + lane;
        #pragma unroll
        for (int mm = 0; mm < 32; ++mm) w0reg[mm] = W0g[mm * 256];
        const float* W1g = W1 + (size_t)c * 64 * 256 + lane;
        #pragma unroll
        for (int mm = 0; mm < 64; ++mm) w1reg[mm] = W1g[mm * 256];
    }

    // ---- block-level compaction of matched atom indices ----
    const unsigned long long bal0 = __ballot(mv0 == c);
    const unsigned long long bal1 = __ballot(mv1 == c);
    if (lane == 0) {
        scnt[w * 2]     = (int)__popcll(bal0);
        scnt[w * 2 + 1] = (int)__popcll(bal1);
    }
    __syncthreads();
    if (tid == 0) {
        int s = 0;
        #pragma unroll
        for (int i = 0; i < 8; ++i) { soff[i] = s; s += scnt[i]; }
        stotal = s;
    }
    __syncthreads();
    {
        const unsigned long long lt = (1ull << lane) - 1ull;  // lane<64 safe
        if (mv0 == c) alist[soff[w * 2]     + (int)__popcll(bal0 & lt)] = w * 128 + lane;
        if (mv1 == c) alist[soff[w * 2 + 1] + (int)__popcll(bal1 & lt)] = w * 128 + 64 + lane;
    }
    __syncthreads();
    const int total   = stotal;
    const int ngroups = (total + 3) >> 2;

    // ---- group loop: round-robin groups across waves, pipelined gather ----
    float zacc = 0.f;   // sum over atoms of silu(h2)[lane]
    const float* x_b = x + (size_t)b * NATOM * DIN;
    const float  sc0 = 0.17677669529663689f;  // 1/sqrt(32)
    const float  sc1 = 0.125f;                // 1/sqrt(64)
    const int    m   = lane & 31;
    const int    jh  = lane >> 5;             // 0 or 1

    float v0 = 0.f, v1 = 0.f;
    if (w < ngroups) {
        int s0 = w * 4 + jh, s1 = s0 + 2;
        int e0 = (s0 < total) ? alist[s0] : -1;
        int e1 = (s1 < total) ? alist[s1] : -1;
        v0 = (e0 >= 0) ? x_b[(size_t)e0 * DIN + m] : 0.f;
        v1 = (e1 >= 0) ? x_b[(size_t)e1 * DIN + m] : 0.f;
    }

    for (int g = w; g < ngroups; g += 4) {
        // current group's x -> LDS (m-major); zero-pad => exact 0 contribution
        xbuf[w][m * 4 + jh]     = v0;
        xbuf[w][m * 4 + jh + 2] = v1;

        // issue NEXT group's gather now; latency hides under the matvecs
        float nv0 = 0.f, nv1 = 0.f;
        if (g + 4 < ngroups) {
            int s0 = (g + 4) * 4 + jh, s1 = s0 + 2;
            int e0 = (s0 < total) ? alist[s0] : -1;
            int e1 = (s1 < total) ? alist[s1] : -1;
            nv0 = (e0 >= 0) ? x_b[(size_t)e0 * DIN + m] : 0.f;
            nv1 = (e1 >= 0) ? x_b[(size_t)e1 * DIN + m] : 0.f;
        }
        // Wave-synchronous LDS handoff: same-wave DS ops execute in order on
        // CDNA; wave_barrier stops the compiler from reordering across it.
        __builtin_amdgcn_wave_barrier();

        // ---- h1[o=lane] for 4 atoms: 32x64 matvec, silu ----
        float h0 = 0.f, h1 = 0.f, h2 = 0.f, h3 = 0.f;
        #pragma unroll
        for (int mm = 0; mm < 32; ++mm) {
            float4 xv = *(const float4*)&xbuf[w][mm * 4];    // uniform addr: broadcast
            float  wv = w0reg[mm];                           // register, free
            h0 += xv.x * wv; h1 += xv.y * wv; h2 += xv.z * wv; h3 += xv.w * wv;
        }
        h0 *= sc0; h1 *= sc0; h2 *= sc0; h3 *= sc0;
        h0 = h0 / (1.f + __expf(-h0));
        h1 = h1 / (1.f + __expf(-h1));
        h2 = h2 / (1.f + __expf(-h2));
        h3 = h3 / (1.f + __expf(-h3));
        *(float4*)&h1buf[w][lane * 4] = make_float4(h0, h1, h2, h3);
        __builtin_amdgcn_wave_barrier();

        // ---- h2[o=lane] for 4 atoms: 64x64 matvec, silu; accumulate ----
        float z0 = 0.f, z1 = 0.f, z2 = 0.f, z3 = 0.f;
        #pragma unroll
        for (int mm = 0; mm < 64; ++mm) {
            float4 hv = *(const float4*)&h1buf[w][mm * 4];   // uniform addr: broadcast
            float  wv = w1reg[mm];
            z0 += hv.x * wv; z1 += hv.y * wv; z2 += hv.z * wv; z3 += hv.w * wv;
        }
        z0 *= sc1; z1 *= sc1; z2 *= sc1; z3 *= sc1;
        zacc += z0 / (1.f + __expf(-z0));
        zacc += z1 / (1.f + __expf(-z1));
        zacc += z2 / (1.f + __expf(-z2));
        zacc += z3 / (1.f + __expf(-z3));
        // keep next iteration's xbuf write below this iteration's LDS reads
        __builtin_amdgcn_wave_barrier();

        v0 = nv0; v1 = nv1;
    }

    // ---- cross-wave h2-sum reduction ----
    hsum[w][lane] = zacc;
    __syncthreads();
    if (tid < 64)
        hsum[0][tid] += hsum[1][tid] + hsum[2][tid] + hsum[3][tid];
    __syncthreads();

    // ---- final 64x128 matvec, once per block, Wout direct from L2 ----
    const int col  = tid & 127;
    const int half = tid >> 7;
    const float* Wo_c = Wo + (size_t)c * 64 * 128 + col;
    float acc = 0.f;
    #pragma unroll
    for (int mm = 0; mm < 32; mm += 4) {
        const int mr = half * 32 + mm;
        float4 hv = *(const float4*)&hsum[0][mr];   // uniform addr: broadcast
        acc += hv.x * Wo_c[(size_t)(mr + 0) * 128];
        acc += hv.y * Wo_c[(size_t)(mr + 1) * 128];
        acc += hv.z * Wo_c[(size_t)(mr + 2) * 128];
        acc += hv.w * Wo_c[(size_t)(mr + 3) * 128];
    }
    fin[half][col] = acc;
    __syncthreads();
    if (tid < 128)
        out[(size_t)b * (NCLS * 128) + c * 128 + tid]
            = (fin[0][tid] + fin[1][tid]) * 0.125f;   // 1/sqrt(HID)
}

extern "C" void kernel_launch(void* const* d_in, const int* in_sizes, int n_in,
                              void* d_out, int out_size, void* d_ws, size_t ws_size,
                              hipStream_t stream) {
    const float* x  = (const float*)d_in[0];
    const float* W0 = (const float*)d_in[1];   // W0_0
    const float* W1 = (const float*)d_in[5];   // W1_0
    const float* Wo = (const float*)d_in[9];   // Wout
    const int*   mp = (const int*)  d_in[10];  // mlp_mapping
    float* outp = (float*)d_out;

    dim3 grid(NCLS, NB);
    eqmlp_fused<<<grid, 256, 0, stream>>>(x, W0, W1, Wo, mp, outp);
}